// Round 6
// baseline (80.688 us; speedup 1.0000x reference)
//
#include <hip/hip_runtime.h>
#include <cstdint>

#define NN 4096
#define FF 512

typedef short bf16x8 __attribute__((ext_vector_type(8)));
typedef float f32x4 __attribute__((ext_vector_type(4)));

__device__ __forceinline__ uint16_t f2bf(float f) {
    uint32_t u = __builtin_bit_cast(uint32_t, f);
    u += 0x7FFFu + ((u >> 16) & 1u);   // round-to-nearest-even
    return (uint16_t)(u >> 16);
}

// ---------------------------------------------------------------------------
// k_prep: Abf[i][j] = bf16(adj[i][j] + (i==j)), d_i = rsqrt(1 + rowsum(adj))
// (row scale d_i applied in k_red; col scale d_j folded into zdT)
// ---------------------------------------------------------------------------
__global__ __launch_bounds__(256) void k_prep(const float* __restrict__ adj,
                                              float* __restrict__ d,
                                              uint16_t* __restrict__ Abf) {
    const int row  = blockIdx.x * 4 + (threadIdx.x >> 6);
    const int lane = threadIdx.x & 63;
    const float4* p = (const float4*)(adj + (size_t)row * NN);
    float4 v[16];
    float s = 0.f;
#pragma unroll
    for (int i = 0; i < 16; ++i) {
        v[i] = p[lane + i * 64];
        s += (v[i].x + v[i].y) + (v[i].z + v[i].w);
    }
#pragma unroll
    for (int off = 1; off < 64; off <<= 1) s += __shfl_xor(s, off);
    const float di = rsqrtf(s + 1.0f);
    if (lane == 0) d[row] = di;
    uint16_t* outp = Abf + (size_t)row * NN;
#pragma unroll
    for (int i = 0; i < 16; ++i) {
        const int cb = (lane + i * 64) * 4;
        float a0 = v[i].x, a1 = v[i].y, a2 = v[i].z, a3 = v[i].w;
        if (cb + 0 == row) a0 += 1.0f;
        if (cb + 1 == row) a1 += 1.0f;
        if (cb + 2 == row) a2 += 1.0f;
        if (cb + 3 == row) a3 += 1.0f;
        ushort4 o;
        o.x = f2bf(a0); o.y = f2bf(a1); o.z = f2bf(a2); o.w = f2bf(a3);
        *(ushort4*)(outp + cb) = o;
    }
}

// ---------------------------------------------------------------------------
// k_xc / k_wc: f32 -> bf16 casts
// ---------------------------------------------------------------------------
__global__ __launch_bounds__(256) void k_xc(const float* __restrict__ x,
                                            uint16_t* __restrict__ xbf) {
    const size_t t4 = (size_t)blockIdx.x * 256 + threadIdx.x;
    float4 v = *(const float4*)(x + t4 * 4);
    ushort4 o;
    o.x = f2bf(v.x); o.y = f2bf(v.y); o.z = f2bf(v.z); o.w = f2bf(v.w);
    *(ushort4*)(xbf + t4 * 4) = o;
}

__global__ __launch_bounds__(256) void k_wc(const float* __restrict__ W,
                                            uint16_t* __restrict__ Wbf) {
    const size_t t4 = (size_t)blockIdx.x * 256 + threadIdx.x;
    float4 v = *(const float4*)(W + t4 * 4);
    ushort4 o;
    o.x = f2bf(v.x); o.y = f2bf(v.y); o.z = f2bf(v.z); o.w = f2bf(v.w);
    *(ushort4*)(Wbf + t4 * 4) = o;
}

// ---------------------------------------------------------------------------
// k_zt: zdT[n][k] = bf16(d[k] * z32[k][n])   (transpose+scale, via LDS)
// ---------------------------------------------------------------------------
__global__ __launch_bounds__(256) void k_zt(const float* __restrict__ z32,
                                            const float* __restrict__ d,
                                            uint16_t* __restrict__ zdT) {
    __shared__ uint16_t t[64][72];
    const int k0 = blockIdx.x * 64;
    const int n0 = blockIdx.y * 64;
    const int tid = threadIdx.x;
    const int r   = tid >> 4;
    const int c4  = tid & 15;
#pragma unroll
    for (int pass = 0; pass < 4; ++pass) {
        const int row = pass * 16 + r;
        float4 v = *(const float4*)(z32 + (size_t)(k0 + row) * FF + n0 + c4 * 4);
        const float dk = d[k0 + row];
        t[c4 * 4 + 0][row] = f2bf(v.x * dk);
        t[c4 * 4 + 1][row] = f2bf(v.y * dk);
        t[c4 * 4 + 2][row] = f2bf(v.z * dk);
        t[c4 * 4 + 3][row] = f2bf(v.w * dk);
    }
    __syncthreads();
#pragma unroll
    for (int pass = 0; pass < 2; ++pass) {
        const int cid = pass * 256 + tid;
        const int n  = cid >> 3;
        const int ch = cid & 7;
        *(uint4*)(zdT + (size_t)(n0 + n) * NN + k0 + ch * 8) = *(const uint4*)&t[n][ch * 8];
    }
}

// ---------------------------------------------------------------------------
// k_mm (m97 structure): C = A[.][K] * Bt[.][K]^T, bf16 operands, f32 out.
// BM=128, BN=64*NW, BK=32, 256 threads = 4 waves (2x2), per-wave 64 x 32*NW.
// 16x16x32 MFMA, 4 x NF frags/wave. SINGLE 16KB-ish LDS buffer, 2 barriers
// per K-step; latency hidden by 2+ co-resident blocks/CU (m114/m97).
// global_load_lds w16; 4-slot XOR chunk swizzle (source-inverse + read).
// Plain f32 stores into outp[ks]; split-K reduced deterministically by k_red.
// ---------------------------------------------------------------------------
template <int BN, int K, int SPLITK>
__global__ __launch_bounds__(256) void k_mm(const uint16_t* __restrict__ A,
                                            const uint16_t* __restrict__ Bt,
                                            float* __restrict__ outp) {
    constexpr int BM    = 128;
    constexpr int MT    = NN / BM;        // 32
    constexpr int NTC   = FF / BN;
    constexpr int KSLEN = K / SPLITK;
    constexpr int NT    = KSLEN / 32;
    constexpr int MTX   = MT / 8;         // 4
    constexpr int NF    = BN / 32;        // frags along n per wave (2 n-waves)
    constexpr int LPT_B = BN / 64;

    __shared__ uint16_t As[BM * 32];
    __shared__ uint16_t Bs[BN * 32];

    // XCD-grouped decode: id&7 = XCD; an m-stripe's (nt,ks) blocks co-run on
    // one XCD -> A stripe L2-resident.
    const int id   = blockIdx.x;
    const int slot = id >> 3;
    const int mt   = (id & 7) * MTX + slot / (NTC * SPLITK);
    const int rem  = slot % (NTC * SPLITK);
    const int nt   = rem % NTC;
    const int ks   = rem / NTC;
    const int m0 = mt * BM;
    const int n0 = nt * BN;
    const int k0 = ks * KSLEN;

    const int tid  = threadIdx.x;
    const int w    = tid >> 6;
    const int lane = tid & 63;
    const int wm = w >> 1, wn = w & 1;

    f32x4 acc[4][NF] = {};

    for (int t = 0; t < NT; ++t) {
        const int ktb = k0 + t * 32;
        // ---- STAGE (A: 8KB -> 2 loads/thread; B: 4KB*LPT_B) ----
#pragma unroll
        for (int i = 0; i < 2; ++i) {
            const int boff = i * 4096 + tid * 16;
            const int row  = boff >> 6;          // 64 B rows
            const int q    = (boff >> 4) & 3;    // LDS chunk slot
            const int c    = q ^ (row & 3);      // global chunk stored there
            const uint16_t* src = A + (size_t)(m0 + row) * K + ktb + c * 8;
            __builtin_amdgcn_global_load_lds(
                (const __attribute__((address_space(1))) void*)src,
                (__attribute__((address_space(3))) void*)&As[boff >> 1],
                16, 0, 0);
        }
#pragma unroll
        for (int i = 0; i < LPT_B; ++i) {
            const int boff = i * 4096 + tid * 16;
            const int row  = boff >> 6;
            const int q    = (boff >> 4) & 3;
            const int c    = q ^ (row & 3);
            const uint16_t* src = Bt + (size_t)(n0 + row) * K + ktb + c * 8;
            __builtin_amdgcn_global_load_lds(
                (const __attribute__((address_space(1))) void*)src,
                (__attribute__((address_space(3))) void*)&Bs[boff >> 1],
                16, 0, 0);
        }
        __syncthreads();   // drains vmcnt -> staged data visible

        // ---- COMPUTE: 8+NF*... ds_read_b128 + 4*NF MFMA ----
        {
            const int cl = lane >> 4;            // k-chunk 0..3
            bf16x8 af[4], bfr[NF];
#pragma unroll
            for (int mf = 0; mf < 4; ++mf) {
                const int r = wm * 64 + mf * 16 + (lane & 15);
                af[mf] = *(const bf16x8*)&As[r * 32 + ((cl ^ (r & 3)) << 3)];
            }
#pragma unroll
            for (int nf = 0; nf < NF; ++nf) {
                const int r = wn * (NF * 16) + nf * 16 + (lane & 15);
                bfr[nf] = *(const bf16x8*)&Bs[r * 32 + ((cl ^ (r & 3)) << 3)];
            }
#pragma unroll
            for (int mf = 0; mf < 4; ++mf)
#pragma unroll
                for (int nf = 0; nf < NF; ++nf)
                    acc[mf][nf] = __builtin_amdgcn_mfma_f32_16x16x32_bf16(
                        af[mf], bfr[nf], acc[mf][nf], 0, 0, 0);
        }
        __syncthreads();   // protect LDS overwrite by next STAGE
    }

    // epilogue: C/D 16x16 layout col=lane&15, row=(lane>>4)*4+r  [m89]
    float* dst = outp + (size_t)ks * NN * FF;
    const int rbase = m0 + wm * 64 + ((lane >> 4) << 2);
    const int cbase = n0 + wn * (NF * 16) + (lane & 15);
#pragma unroll
    for (int mf = 0; mf < 4; ++mf) {
#pragma unroll
        for (int nf = 0; nf < NF; ++nf) {
            const int col = cbase + nf * 16;
#pragma unroll
            for (int r = 0; r < 4; ++r) {
                const int row = rbase + mf * 16 + r;
                dst[(size_t)row * FF + col] = acc[mf][nf][r];
            }
        }
    }
}

// ---------------------------------------------------------------------------
// k_red: out[i][j] = d[i] * (p0+p1+p2+p3)[i][j] + b[j]
// ---------------------------------------------------------------------------
__global__ __launch_bounds__(256) void k_red(const float* __restrict__ parts,
                                             const float* __restrict__ d,
                                             const float* __restrict__ b,
                                             float* __restrict__ out) {
    constexpr size_t STRIDE = (size_t)NN * FF;
    const size_t g   = (size_t)blockIdx.x * 256 + threadIdx.x;   // float4 id
    const int    row = (int)((g * 4) >> 9);
    const int    col = (int)((g * 4) & 511);
    float4 s = *(const float4*)(parts + g * 4);
#pragma unroll
    for (int p = 1; p < 4; ++p) {
        float4 v = *(const float4*)(parts + p * STRIDE + g * 4);
        s.x += v.x; s.y += v.y; s.z += v.z; s.w += v.w;
    }
    const float di = d[row];
    const float4 bv = *(const float4*)(b + col);
    float4 o;
    o.x = s.x * di + bv.x;
    o.y = s.y * di + bv.y;
    o.z = s.z * di + bv.z;
    o.w = s.w * di + bv.w;
    *(float4*)(out + g * 4) = o;
}

// ---------------------------------------------------------------------------
extern "C" void kernel_launch(void* const* d_in, const int* in_sizes, int n_in,
                              void* d_out, int out_size, void* d_ws, size_t ws_size,
                              hipStream_t stream) {
    const float* x   = (const float*)d_in[0];   // [4096][512]
    const float* adj = (const float*)d_in[1];   // [4096][4096]
    const float* W   = (const float*)d_in[2];   // [512][512]
    const float* b   = (const float*)d_in[3];   // [512]
    float* out = (float*)d_out;                 // [4096][512] f32

    char* ws = (char*)d_ws;
    float*    d_    = (float*)ws;                                 // 16 KB (pad 64K)
    uint16_t* Abf   = (uint16_t*)(ws + 65536);                    // 32 MB
    uint16_t* zdT   = Abf + (size_t)NN * NN;                      // 4 MB
    uint16_t* xbf   = zdT + (size_t)FF * NN;                      // 4 MB
    uint16_t* Wbf   = xbf + (size_t)NN * FF;                      // 0.5 MB
    float*    z32   = (float*)(Wbf + (size_t)FF * FF);            // 8 MB
    float*    parts = z32 + (size_t)NN * FF;                      // 32 MB (4 x 8MB)

    k_wc<<<FF * FF / 1024, 256, 0, stream>>>(W, Wbf);
    k_xc<<<NN * FF / 1024, 256, 0, stream>>>(x, xbf);
    k_prep<<<NN / 4, 256, 0, stream>>>(adj, d_, Abf);
    // z = x @ W^T  (BN=64, no split, 512 blocks, plain stores)
    k_mm<64, FF, 1><<<512, 256, 0, stream>>>(xbf, Wbf, z32);
    // zdT[n][k] = d_k * z[k][n] in bf16
    k_zt<<<dim3(NN / 64, FF / 64), 256, 0, stream>>>(z32, d_, zdT);
    // parts[ks] = A @ zdT^T (k-slice ks): BN=128, split-K=4, 512 blocks
    k_mm<128, NN, 4><<<512, 256, 0, stream>>>(Abf, zdT, parts);
    // out = d[i] * sum(parts) + b
    k_red<<<NN * FF / 1024, 256, 0, stream>>>(parts, d_, b, out);
}

// Round 7
// 71.166 us; speedup vs baseline: 1.1338x; 1.1338x over previous
//
#include <hip/hip_runtime.h>
#include <cstdint>

#define NN 4096
#define FF 512

typedef short bf16x8 __attribute__((ext_vector_type(8)));
typedef float f32x4 __attribute__((ext_vector_type(4)));

__device__ __forceinline__ uint16_t f2bf(float f) {
    uint32_t u = __builtin_bit_cast(uint32_t, f);
    u += 0x7FFFu + ((u >> 16) & 1u);   // round-to-nearest-even
    return (uint16_t)(u >> 16);
}

// ---------------------------------------------------------------------------
// k_prep: Abf[i][j] = bf16(adj[i][j] + (i==j)), d_i = rsqrt(1 + rowsum(adj))
// ---------------------------------------------------------------------------
__global__ __launch_bounds__(256) void k_prep(const float* __restrict__ adj,
                                              float* __restrict__ d,
                                              uint16_t* __restrict__ Abf) {
    const int row  = blockIdx.x * 4 + (threadIdx.x >> 6);
    const int lane = threadIdx.x & 63;
    const float4* p = (const float4*)(adj + (size_t)row * NN);
    float4 v[16];
    float s = 0.f;
#pragma unroll
    for (int i = 0; i < 16; ++i) {
        v[i] = p[lane + i * 64];
        s += (v[i].x + v[i].y) + (v[i].z + v[i].w);
    }
#pragma unroll
    for (int off = 1; off < 64; off <<= 1) s += __shfl_xor(s, off);
    const float di = rsqrtf(s + 1.0f);
    if (lane == 0) d[row] = di;
    uint16_t* outp = Abf + (size_t)row * NN;
#pragma unroll
    for (int i = 0; i < 16; ++i) {
        const int cb = (lane + i * 64) * 4;
        float a0 = v[i].x, a1 = v[i].y, a2 = v[i].z, a3 = v[i].w;
        if (cb + 0 == row) a0 += 1.0f;
        if (cb + 1 == row) a1 += 1.0f;
        if (cb + 2 == row) a2 += 1.0f;
        if (cb + 3 == row) a3 += 1.0f;
        ushort4 o;
        o.x = f2bf(a0); o.y = f2bf(a1); o.z = f2bf(a2); o.w = f2bf(a3);
        *(ushort4*)(outp + cb) = o;
    }
}

// ---------------------------------------------------------------------------
// k_xc / k_wc: f32 -> bf16 casts
// ---------------------------------------------------------------------------
__global__ __launch_bounds__(256) void k_xc(const float* __restrict__ x,
                                            uint16_t* __restrict__ xbf) {
    const size_t t4 = (size_t)blockIdx.x * 256 + threadIdx.x;
    float4 v = *(const float4*)(x + t4 * 4);
    ushort4 o;
    o.x = f2bf(v.x); o.y = f2bf(v.y); o.z = f2bf(v.z); o.w = f2bf(v.w);
    *(ushort4*)(xbf + t4 * 4) = o;
}

__global__ __launch_bounds__(256) void k_wc(const float* __restrict__ W,
                                            uint16_t* __restrict__ Wbf) {
    const size_t t4 = (size_t)blockIdx.x * 256 + threadIdx.x;
    float4 v = *(const float4*)(W + t4 * 4);
    ushort4 o;
    o.x = f2bf(v.x); o.y = f2bf(v.y); o.z = f2bf(v.z); o.w = f2bf(v.w);
    *(ushort4*)(Wbf + t4 * 4) = o;
}

// ---------------------------------------------------------------------------
// k_zt: zdT[n][k] = bf16(d[k] * z32[k][n])   (transpose+scale, via LDS)
// ---------------------------------------------------------------------------
__global__ __launch_bounds__(256) void k_zt(const float* __restrict__ z32,
                                            const float* __restrict__ d,
                                            uint16_t* __restrict__ zdT) {
    __shared__ uint16_t t[64][72];
    const int k0 = blockIdx.x * 64;
    const int n0 = blockIdx.y * 64;
    const int tid = threadIdx.x;
    const int r   = tid >> 4;
    const int c4  = tid & 15;
#pragma unroll
    for (int pass = 0; pass < 4; ++pass) {
        const int row = pass * 16 + r;
        float4 v = *(const float4*)(z32 + (size_t)(k0 + row) * FF + n0 + c4 * 4);
        const float dk = d[k0 + row];
        t[c4 * 4 + 0][row] = f2bf(v.x * dk);
        t[c4 * 4 + 1][row] = f2bf(v.y * dk);
        t[c4 * 4 + 2][row] = f2bf(v.z * dk);
        t[c4 * 4 + 3][row] = f2bf(v.w * dk);
    }
    __syncthreads();
#pragma unroll
    for (int pass = 0; pass < 2; ++pass) {
        const int cid = pass * 256 + tid;
        const int n  = cid >> 3;
        const int ch = cid & 7;
        *(uint4*)(zdT + (size_t)(n0 + n) * NN + k0 + ch * 8) = *(const uint4*)&t[n][ch * 8];
    }
}

// ---------------------------------------------------------------------------
// k_mm (m97 structure, m97 occupancy): C = A[.][K] * Bt[.][K]^T, bf16 in, f32 out.
// BK=64, 256 threads = 4 waves (2x2), 16x16x32 MFMA.
// SINGLE LDS buffer, plain 2-barrier loop (compiler schedules lgkmcnt finely;
// barrier drain hidden by 4 co-resident blocks/CU — m114). launch_bounds(256,4)
// keeps VGPR<=128 so 16 waves/CU fit. gload_lds w16; 8-slot XOR chunk swizzle
// (source-inverse + read-side) on 128B rows [R1-verified].
// Plain f32 stores into outp[ks]; split-K reduced deterministically by k_red.
// ---------------------------------------------------------------------------
template <int BM, int BN, int K, int SPLITK>
__global__ __launch_bounds__(256, 4) void k_mm(const uint16_t* __restrict__ A,
                                               const uint16_t* __restrict__ Bt,
                                               float* __restrict__ outp) {
    constexpr int MT    = NN / BM;
    constexpr int NTC   = FF / BN;
    constexpr int KSLEN = K / SPLITK;
    constexpr int NT    = KSLEN / 64;
    constexpr int MTX   = MT / 8;
    constexpr int MFR   = BM / 32;     // m-frags per wave (2 m-waves, 16 rows/frag)
    constexpr int NFR   = BN / 32;     // n-frags per wave (2 n-waves)
    constexpr int LPT_A = BM / 32;     // gload_lds per thread (A tile = BM*128B)
    constexpr int LPT_B = BN / 32;

    __shared__ uint16_t As[BM * 64];
    __shared__ uint16_t Bs[BN * 64];

    // XCD-grouped decode: id&7 = XCD; an m-stripe's (nt,ks) blocks co-run on
    // one XCD -> A stripe L2-resident.
    const int id   = blockIdx.x;
    const int slot = id >> 3;
    const int mt   = (id & 7) * MTX + slot / (NTC * SPLITK);
    const int rem  = slot % (NTC * SPLITK);
    const int nt   = rem % NTC;
    const int ks   = rem / NTC;
    const int m0 = mt * BM;
    const int n0 = nt * BN;
    const int k0 = ks * KSLEN;

    const int tid  = threadIdx.x;
    const int w    = tid >> 6;
    const int lane = tid & 63;
    const int wm = w >> 1, wn = w & 1;

    f32x4 acc[MFR][NFR] = {};

    for (int t = 0; t < NT; ++t) {
        const int ktb = k0 + t * 64;
        // ---- STAGE: A tile BM*128B, B tile BN*128B, 16B/lane loads ----
#pragma unroll
        for (int i = 0; i < LPT_A; ++i) {
            const int boff = i * 4096 + tid * 16;
            const int row  = boff >> 7;          // 128 B rows
            const int q    = (boff >> 4) & 7;    // LDS chunk slot
            const int c    = q ^ (row & 7);      // global chunk stored there
            const uint16_t* src = A + (size_t)(m0 + row) * K + ktb + c * 8;
            __builtin_amdgcn_global_load_lds(
                (const __attribute__((address_space(1))) void*)src,
                (__attribute__((address_space(3))) void*)&As[boff >> 1],
                16, 0, 0);
        }
#pragma unroll
        for (int i = 0; i < LPT_B; ++i) {
            const int boff = i * 4096 + tid * 16;
            const int row  = boff >> 7;
            const int q    = (boff >> 4) & 7;
            const int c    = q ^ (row & 7);
            const uint16_t* src = Bt + (size_t)(n0 + row) * K + ktb + c * 8;
            __builtin_amdgcn_global_load_lds(
                (const __attribute__((address_space(1))) void*)src,
                (__attribute__((address_space(3))) void*)&Bs[boff >> 1],
                16, 0, 0);
        }
        __syncthreads();   // drains vmcnt -> staged data visible

        // ---- COMPUTE: 2 k-chunks of 32 ----
#pragma unroll
        for (int kk = 0; kk < 2; ++kk) {
            const int cl = kk * 4 + (lane >> 4);   // k-chunk 0..7
            bf16x8 af[MFR], bfr[NFR];
#pragma unroll
            for (int mf = 0; mf < MFR; ++mf) {
                const int r = wm * (MFR * 16) + mf * 16 + (lane & 15);
                af[mf] = *(const bf16x8*)&As[r * 64 + ((cl ^ (r & 7)) << 3)];
            }
#pragma unroll
            for (int nf = 0; nf < NFR; ++nf) {
                const int r = wn * (NFR * 16) + nf * 16 + (lane & 15);
                bfr[nf] = *(const bf16x8*)&Bs[r * 64 + ((cl ^ (r & 7)) << 3)];
            }
#pragma unroll
            for (int mf = 0; mf < MFR; ++mf)
#pragma unroll
                for (int nf = 0; nf < NFR; ++nf)
                    acc[mf][nf] = __builtin_amdgcn_mfma_f32_16x16x32_bf16(
                        af[mf], bfr[nf], acc[mf][nf], 0, 0, 0);
        }
        __syncthreads();   // protect LDS overwrite by next STAGE
    }

    // epilogue: C/D 16x16 layout col=lane&15, row=(lane>>4)*4+r  [m89]
    float* dst = outp + (size_t)ks * NN * FF;
    const int rbase = m0 + wm * (MFR * 16) + ((lane >> 4) << 2);
    const int cbase = n0 + wn * (NFR * 16) + (lane & 15);
#pragma unroll
    for (int mf = 0; mf < MFR; ++mf) {
#pragma unroll
        for (int nf = 0; nf < NFR; ++nf) {
            const int col = cbase + nf * 16;
#pragma unroll
            for (int r = 0; r < 4; ++r) {
                const int row = rbase + mf * 16 + r;
                dst[(size_t)row * FF + col] = acc[mf][nf][r];
            }
        }
    }
}

// ---------------------------------------------------------------------------
// k_red: out[i][j] = d[i] * (p0+p1+p2+p3)[i][j] + b[j]
// ---------------------------------------------------------------------------
__global__ __launch_bounds__(256) void k_red(const float* __restrict__ parts,
                                             const float* __restrict__ d,
                                             const float* __restrict__ b,
                                             float* __restrict__ out) {
    constexpr size_t STRIDE = (size_t)NN * FF;
    const size_t g   = (size_t)blockIdx.x * 256 + threadIdx.x;   // float4 id
    const int    row = (int)((g * 4) >> 9);
    const int    col = (int)((g * 4) & 511);
    float4 s = *(const float4*)(parts + g * 4);
#pragma unroll
    for (int p = 1; p < 4; ++p) {
        float4 v = *(const float4*)(parts + p * STRIDE + g * 4);
        s.x += v.x; s.y += v.y; s.z += v.z; s.w += v.w;
    }
    const float di = d[row];
    const float4 bv = *(const float4*)(b + col);
    float4 o;
    o.x = s.x * di + bv.x;
    o.y = s.y * di + bv.y;
    o.z = s.z * di + bv.z;
    o.w = s.w * di + bv.w;
    *(float4*)(out + g * 4) = o;
}

// ---------------------------------------------------------------------------
extern "C" void kernel_launch(void* const* d_in, const int* in_sizes, int n_in,
                              void* d_out, int out_size, void* d_ws, size_t ws_size,
                              hipStream_t stream) {
    const float* x   = (const float*)d_in[0];   // [4096][512]
    const float* adj = (const float*)d_in[1];   // [4096][4096]
    const float* W   = (const float*)d_in[2];   // [512][512]
    const float* b   = (const float*)d_in[3];   // [512]
    float* out = (float*)d_out;                 // [4096][512] f32

    char* ws = (char*)d_ws;
    float*    d_    = (float*)ws;                                 // 16 KB (pad 64K)
    uint16_t* Abf   = (uint16_t*)(ws + 65536);                    // 32 MB
    uint16_t* zdT   = Abf + (size_t)NN * NN;                      // 4 MB
    uint16_t* xbf   = zdT + (size_t)FF * NN;                      // 4 MB
    uint16_t* Wbf   = xbf + (size_t)NN * FF;                      // 0.5 MB
    float*    z32   = (float*)(Wbf + (size_t)FF * FF);            // 8 MB
    float*    parts = z32 + (size_t)NN * FF;                      // 32 MB (4 x 8MB)

    k_wc<<<FF * FF / 1024, 256, 0, stream>>>(W, Wbf);
    k_xc<<<NN * FF / 1024, 256, 0, stream>>>(x, xbf);
    k_prep<<<NN / 4, 256, 0, stream>>>(adj, d_, Abf);
    // z = x @ W^T  (BM=64, BN=64, no split, 512 blocks = 2/CU)
    k_mm<64, 64, FF, 1><<<512, 256, 0, stream>>>(xbf, Wbf, z32);
    // zdT[n][k] = d_k * z[k][n] in bf16
    k_zt<<<dim3(NN / 64, FF / 64), 256, 0, stream>>>(z32, d_, zdT);
    // parts[ks] = A @ zdT^T: BM=128, BN=64, split-K=4 -> 1024 blocks = 4/CU
    k_mm<128, 64, NN, 4><<<1024, 256, 0, stream>>>(Abf, zdT, parts);
    // out = d[i] * sum(parts) + b
    k_red<<<NN * FF / 1024, 256, 0, stream>>>(parts, d_, b, out);
}

// Round 8
// 68.869 us; speedup vs baseline: 1.1716x; 1.0334x over previous
//
#include <hip/hip_runtime.h>
#include <cstdint>

#define NN 4096
#define FF 512

typedef short bf16x8 __attribute__((ext_vector_type(8)));
typedef float f32x4 __attribute__((ext_vector_type(4)));

__device__ __forceinline__ uint16_t f2bf(float f) {
    uint32_t u = __builtin_bit_cast(uint32_t, f);
    u += 0x7FFFu + ((u >> 16) & 1u);   // round-to-nearest-even
    return (uint16_t)(u >> 16);
}
__device__ __forceinline__ float bf2f(uint16_t h) {
    uint32_t u = (uint32_t)h << 16;
    return __builtin_bit_cast(float, u);
}

// ---------------------------------------------------------------------------
// k_prep: Abf[i][j] = bf16(adj[i][j] + (i==j)), d_i = rsqrt(1 + rowsum(adj))
// ---------------------------------------------------------------------------
__global__ __launch_bounds__(256) void k_prep(const float* __restrict__ adj,
                                              float* __restrict__ d,
                                              uint16_t* __restrict__ Abf) {
    const int row  = blockIdx.x * 4 + (threadIdx.x >> 6);
    const int lane = threadIdx.x & 63;
    const float4* p = (const float4*)(adj + (size_t)row * NN);
    float4 v[16];
    float s = 0.f;
#pragma unroll
    for (int i = 0; i < 16; ++i) {
        v[i] = p[lane + i * 64];
        s += (v[i].x + v[i].y) + (v[i].z + v[i].w);
    }
#pragma unroll
    for (int off = 1; off < 64; off <<= 1) s += __shfl_xor(s, off);
    const float di = rsqrtf(s + 1.0f);
    if (lane == 0) d[row] = di;
    uint16_t* outp = Abf + (size_t)row * NN;
#pragma unroll
    for (int i = 0; i < 16; ++i) {
        const int cb = (lane + i * 64) * 4;
        float a0 = v[i].x, a1 = v[i].y, a2 = v[i].z, a3 = v[i].w;
        if (cb + 0 == row) a0 += 1.0f;
        if (cb + 1 == row) a1 += 1.0f;
        if (cb + 2 == row) a2 += 1.0f;
        if (cb + 3 == row) a3 += 1.0f;
        ushort4 o;
        o.x = f2bf(a0); o.y = f2bf(a1); o.z = f2bf(a2); o.w = f2bf(a3);
        *(ushort4*)(outp + cb) = o;
    }
}

// ---------------------------------------------------------------------------
// k_xc / k_wc: f32 -> bf16 casts
// ---------------------------------------------------------------------------
__global__ __launch_bounds__(256) void k_xc(const float* __restrict__ x,
                                            uint16_t* __restrict__ xbf) {
    const size_t t4 = (size_t)blockIdx.x * 256 + threadIdx.x;
    float4 v = *(const float4*)(x + t4 * 4);
    ushort4 o;
    o.x = f2bf(v.x); o.y = f2bf(v.y); o.z = f2bf(v.z); o.w = f2bf(v.w);
    *(ushort4*)(xbf + t4 * 4) = o;
}

__global__ __launch_bounds__(256) void k_wc(const float* __restrict__ W,
                                            uint16_t* __restrict__ Wbf) {
    const size_t t4 = (size_t)blockIdx.x * 256 + threadIdx.x;
    float4 v = *(const float4*)(W + t4 * 4);
    ushort4 o;
    o.x = f2bf(v.x); o.y = f2bf(v.y); o.z = f2bf(v.z); o.w = f2bf(v.w);
    *(ushort4*)(Wbf + t4 * 4) = o;
}

// ---------------------------------------------------------------------------
// k_zt: zdT[n][k] = bf16(d[k] * z32[k][n])   (transpose+scale, via LDS)
// ---------------------------------------------------------------------------
__global__ __launch_bounds__(256) void k_zt(const float* __restrict__ z32,
                                            const float* __restrict__ d,
                                            uint16_t* __restrict__ zdT) {
    __shared__ uint16_t t[64][72];
    const int k0 = blockIdx.x * 64;
    const int n0 = blockIdx.y * 64;
    const int tid = threadIdx.x;
    const int r   = tid >> 4;
    const int c4  = tid & 15;
#pragma unroll
    for (int pass = 0; pass < 4; ++pass) {
        const int row = pass * 16 + r;
        float4 v = *(const float4*)(z32 + (size_t)(k0 + row) * FF + n0 + c4 * 4);
        const float dk = d[k0 + row];
        t[c4 * 4 + 0][row] = f2bf(v.x * dk);
        t[c4 * 4 + 1][row] = f2bf(v.y * dk);
        t[c4 * 4 + 2][row] = f2bf(v.z * dk);
        t[c4 * 4 + 3][row] = f2bf(v.w * dk);
    }
    __syncthreads();
#pragma unroll
    for (int pass = 0; pass < 2; ++pass) {
        const int cid = pass * 256 + tid;
        const int n  = cid >> 3;
        const int ch = cid & 7;
        *(uint4*)(zdT + (size_t)(n0 + n) * NN + k0 + ch * 8) = *(const uint4*)&t[n][ch * 8];
    }
}

// ---------------------------------------------------------------------------
// k_mm (small GEMM, R7-verified): C = A[.][K] * Bt[.][K]^T, f32 out.
// ---------------------------------------------------------------------------
template <int BM, int BN, int K>
__global__ __launch_bounds__(256, 4) void k_mm(const uint16_t* __restrict__ A,
                                               const uint16_t* __restrict__ Bt,
                                               float* __restrict__ outp) {
    constexpr int NTC   = FF / BN;
    constexpr int NT    = K / 64;
    constexpr int MFR   = BM / 32;
    constexpr int NFR   = BN / 32;
    constexpr int LPT_A = BM / 32;
    constexpr int LPT_B = BN / 32;

    __shared__ uint16_t As[BM * 64];
    __shared__ uint16_t Bs[BN * 64];

    const int id   = blockIdx.x;
    const int mt   = id / NTC;
    const int nt   = id % NTC;
    const int m0 = mt * BM;
    const int n0 = nt * BN;

    const int tid  = threadIdx.x;
    const int w    = tid >> 6;
    const int lane = tid & 63;
    const int wm = w >> 1, wn = w & 1;

    f32x4 acc[MFR][NFR] = {};

    for (int t = 0; t < NT; ++t) {
        const int ktb = t * 64;
#pragma unroll
        for (int i = 0; i < LPT_A; ++i) {
            const int boff = i * 4096 + tid * 16;
            const int row  = boff >> 7;
            const int q    = (boff >> 4) & 7;
            const int c    = q ^ (row & 7);
            const uint16_t* src = A + (size_t)(m0 + row) * K + ktb + c * 8;
            __builtin_amdgcn_global_load_lds(
                (const __attribute__((address_space(1))) void*)src,
                (__attribute__((address_space(3))) void*)&As[boff >> 1],
                16, 0, 0);
        }
#pragma unroll
        for (int i = 0; i < LPT_B; ++i) {
            const int boff = i * 4096 + tid * 16;
            const int row  = boff >> 7;
            const int q    = (boff >> 4) & 7;
            const int c    = q ^ (row & 7);
            const uint16_t* src = Bt + (size_t)(n0 + row) * K + ktb + c * 8;
            __builtin_amdgcn_global_load_lds(
                (const __attribute__((address_space(1))) void*)src,
                (__attribute__((address_space(3))) void*)&Bs[boff >> 1],
                16, 0, 0);
        }
        __syncthreads();
#pragma unroll
        for (int kk = 0; kk < 2; ++kk) {
            const int cl = kk * 4 + (lane >> 4);
            bf16x8 af[MFR], bfr[NFR];
#pragma unroll
            for (int mf = 0; mf < MFR; ++mf) {
                const int r = wm * (MFR * 16) + mf * 16 + (lane & 15);
                af[mf] = *(const bf16x8*)&As[r * 64 + ((cl ^ (r & 7)) << 3)];
            }
#pragma unroll
            for (int nf = 0; nf < NFR; ++nf) {
                const int r = wn * (NFR * 16) + nf * 16 + (lane & 15);
                bfr[nf] = *(const bf16x8*)&Bs[r * 64 + ((cl ^ (r & 7)) << 3)];
            }
#pragma unroll
            for (int mf = 0; mf < MFR; ++mf)
#pragma unroll
                for (int nf = 0; nf < NFR; ++nf)
                    acc[mf][nf] = __builtin_amdgcn_mfma_f32_16x16x32_bf16(
                        af[mf], bfr[nf], acc[mf][nf], 0, 0, 0);
        }
        __syncthreads();
    }

    const int rbase = m0 + wm * (MFR * 16) + ((lane >> 4) << 2);
    const int cbase = n0 + wn * (NFR * 16) + (lane & 15);
#pragma unroll
    for (int mf = 0; mf < MFR; ++mf)
#pragma unroll
        for (int nf = 0; nf < NFR; ++nf) {
            const int col = cbase + nf * 16;
#pragma unroll
            for (int r = 0; r < 4; ++r) {
                const int row = rbase + mf * 16 + r;
                outp[(size_t)row * FF + col] = acc[mf][nf][r];
            }
        }
}

// ---------------------------------------------------------------------------
// k_mmx (big GEMM): parts[ks] = A[4096][kslice] * Bt[512][kslice]^T, bf16 out.
// BM=256, BN=128, BK=64, 512 threads = 8 waves (4m x 2n), wave tile 64x64
// (4x4 of 16x16x32 frags -> 2:1 FLOP:LDS-byte, m97 ratio).
// RING-3 LDS (144 KB), stage t+2 each iter, counted vmcnt(12) steady state —
// never drains to 0 in the main loop (T3/T4). Race-free: stage(t+2) overwrites
// the buffer read at iter t-1, fenced by that iter's end barrier; ds_reads are
// consumed by MFMA before the barrier (compiler lgkmcnt).
// Split-K=4; XCD grouped by (ks, mt-parity): per-XCD set ~5 MB.
// ---------------------------------------------------------------------------
__global__ __launch_bounds__(512, 1) void k_mmx(const uint16_t* __restrict__ A,
                                                const uint16_t* __restrict__ Bt,
                                                uint16_t* __restrict__ parts) {
    constexpr int BM = 256, BN = 128, K = NN;
    constexpr int KSLEN = K / 4;       // 1024
    constexpr int NT    = KSLEN / 64;  // 16

    __shared__ uint16_t As[3][BM * 64];   // 3 x 32 KB
    __shared__ uint16_t Bs[3][BN * 64];   // 3 x 16 KB

    // decode: xcd = id&7 = (ks<<1)|(mt&1); slot: mt_hi, nt
    const int id   = blockIdx.x;          // 0..255
    const int xcd  = id & 7;
    const int slot = id >> 3;             // 0..31
    const int ks   = xcd >> 1;            // 0..3
    const int mt   = ((slot >> 2) << 1) | (xcd & 1);   // 0..15
    const int nt   = slot & 3;            // 0..3
    const int m0 = mt * BM;
    const int n0 = nt * BN;
    const int k0 = ks * KSLEN;

    const int tid  = threadIdx.x;
    const int w    = tid >> 6;
    const int lane = tid & 63;
    const int wm = w >> 1, wn = w & 1;    // 4m x 2n

    f32x4 acc[4][4] = {};

    auto STAGE = [&](int t, int buf) {
        const int ktb = k0 + t * 64;
#pragma unroll
        for (int i = 0; i < 4; ++i) {      // A: 32 KB
            const int boff = i * 8192 + tid * 16;
            const int row  = boff >> 7;    // 0..255
            const int q    = (boff >> 4) & 7;
            const int c    = q ^ (row & 7);
            const uint16_t* src = A + (size_t)(m0 + row) * K + ktb + c * 8;
            __builtin_amdgcn_global_load_lds(
                (const __attribute__((address_space(1))) void*)src,
                (__attribute__((address_space(3))) void*)&As[buf][boff >> 1],
                16, 0, 0);
        }
#pragma unroll
        for (int i = 0; i < 2; ++i) {      // B: 16 KB
            const int boff = i * 8192 + tid * 16;
            const int row  = boff >> 7;    // 0..127
            const int q    = (boff >> 4) & 7;
            const int c    = q ^ (row & 7);
            const uint16_t* src = Bt + (size_t)(n0 + row) * K + ktb + c * 8;
            __builtin_amdgcn_global_load_lds(
                (const __attribute__((address_space(1))) void*)src,
                (__attribute__((address_space(3))) void*)&Bs[buf][boff >> 1],
                16, 0, 0);
        }
    };

    auto COMPUTE = [&](int buf) {
#pragma unroll
        for (int kk = 0; kk < 2; ++kk) {
            const int cl = kk * 4 + (lane >> 4);
            bf16x8 af[4], bfr[4];
#pragma unroll
            for (int mf = 0; mf < 4; ++mf) {
                const int r = wm * 64 + mf * 16 + (lane & 15);
                af[mf] = *(const bf16x8*)&As[buf][r * 64 + ((cl ^ (r & 7)) << 3)];
            }
#pragma unroll
            for (int nf = 0; nf < 4; ++nf) {
                const int r = wn * 64 + nf * 16 + (lane & 15);
                bfr[nf] = *(const bf16x8*)&Bs[buf][r * 64 + ((cl ^ (r & 7)) << 3)];
            }
#pragma unroll
            for (int mf = 0; mf < 4; ++mf)
#pragma unroll
                for (int nf = 0; nf < 4; ++nf)
                    acc[mf][nf] = __builtin_amdgcn_mfma_f32_16x16x32_bf16(
                        af[mf], bfr[nf], acc[mf][nf], 0, 0, 0);
        }
    };

    STAGE(0, 0);
    STAGE(1, 1);
    int sb = 2, cb = 0;
    for (int t = 0; t < NT; ++t) {
        if (t + 2 < NT) {
            STAGE(t + 2, sb);
            sb = (sb == 2) ? 0 : sb + 1;
            asm volatile("s_waitcnt vmcnt(12)" ::: "memory");  // tiles t+1,t+2 in flight
        } else if (t + 2 == NT) {
            asm volatile("s_waitcnt vmcnt(6)" ::: "memory");   // tile t+1 in flight
        } else {
            asm volatile("s_waitcnt vmcnt(0)" ::: "memory");
        }
        __builtin_amdgcn_s_barrier();
        COMPUTE(cb);
        cb = (cb == 2) ? 0 : cb + 1;
        __builtin_amdgcn_s_barrier();
    }

    // epilogue: bf16 partials. C/D: col=lane&15, row=(lane>>4)*4+r
    uint16_t* dst = parts + (size_t)ks * NN * FF;
    const int rbase = m0 + wm * 64 + ((lane >> 4) << 2);
    const int cbase = n0 + wn * 64 + (lane & 15);
#pragma unroll
    for (int mf = 0; mf < 4; ++mf)
#pragma unroll
        for (int nf = 0; nf < 4; ++nf) {
            const int col = cbase + nf * 16;
#pragma unroll
            for (int r = 0; r < 4; ++r) {
                const int row = rbase + mf * 16 + r;
                dst[(size_t)row * FF + col] = f2bf(acc[mf][nf][r]);
            }
        }
}

// ---------------------------------------------------------------------------
// k_red: out[i][j] = d[i] * sum_p bf2f(parts[p][i][j]) + b[j]
// ---------------------------------------------------------------------------
__global__ __launch_bounds__(256) void k_red(const uint16_t* __restrict__ parts,
                                             const float* __restrict__ d,
                                             const float* __restrict__ b,
                                             float* __restrict__ out) {
    constexpr size_t STRIDE = (size_t)NN * FF;
    const size_t g   = (size_t)blockIdx.x * 256 + threadIdx.x;   // ushort8 id
    const int    row = (int)((g * 8) >> 9);
    const int    col = (int)((g * 8) & 511);
    float s[8] = {};
#pragma unroll
    for (int p = 0; p < 4; ++p) {
        ushort4 v0 = *(const ushort4*)(parts + p * STRIDE + g * 8);
        ushort4 v1 = *(const ushort4*)(parts + p * STRIDE + g * 8 + 4);
        s[0] += bf2f(v0.x); s[1] += bf2f(v0.y); s[2] += bf2f(v0.z); s[3] += bf2f(v0.w);
        s[4] += bf2f(v1.x); s[5] += bf2f(v1.y); s[6] += bf2f(v1.z); s[7] += bf2f(v1.w);
    }
    const float di = d[row];
    float4 o0, o1;
    o0.x = s[0] * di + b[col + 0];
    o0.y = s[1] * di + b[col + 1];
    o0.z = s[2] * di + b[col + 2];
    o0.w = s[3] * di + b[col + 3];
    o1.x = s[4] * di + b[col + 4];
    o1.y = s[5] * di + b[col + 5];
    o1.z = s[6] * di + b[col + 6];
    o1.w = s[7] * di + b[col + 7];
    *(float4*)(out + g * 8)     = o0;
    *(float4*)(out + g * 8 + 4) = o1;
}

// ---------------------------------------------------------------------------
extern "C" void kernel_launch(void* const* d_in, const int* in_sizes, int n_in,
                              void* d_out, int out_size, void* d_ws, size_t ws_size,
                              hipStream_t stream) {
    const float* x   = (const float*)d_in[0];   // [4096][512]
    const float* adj = (const float*)d_in[1];   // [4096][4096]
    const float* W   = (const float*)d_in[2];   // [512][512]
    const float* b   = (const float*)d_in[3];   // [512]
    float* out = (float*)d_out;                 // [4096][512] f32

    char* ws = (char*)d_ws;
    float*    d_    = (float*)ws;                                 // 16 KB (pad 64K)
    uint16_t* Abf   = (uint16_t*)(ws + 65536);                    // 32 MB
    uint16_t* zdT   = Abf + (size_t)NN * NN;                      // 4 MB
    uint16_t* xbf   = zdT + (size_t)FF * NN;                      // 4 MB
    uint16_t* Wbf   = xbf + (size_t)NN * FF;                      // 0.5 MB
    float*    z32   = (float*)(Wbf + (size_t)FF * FF);            // 8 MB
    uint16_t* parts = (uint16_t*)(z32 + (size_t)NN * FF);         // 16 MB (4 x 4MB bf16)

    k_wc<<<FF * FF / 1024, 256, 0, stream>>>(W, Wbf);
    k_xc<<<NN * FF / 1024, 256, 0, stream>>>(x, xbf);
    k_prep<<<NN / 4, 256, 0, stream>>>(adj, d_, Abf);
    // z = x @ W^T  (BM=64, BN=64, 512 blocks = 2/CU)
    k_mm<64, 64, FF><<<512, 256, 0, stream>>>(xbf, Wbf, z32);
    // zdT[n][k] = d_k * z[k][n] in bf16
    k_zt<<<dim3(NN / 64, FF / 64), 256, 0, stream>>>(z32, d_, zdT);
    // parts[ks] = A @ zdT^T (k-slice ks): ring-3 pipelined, bf16 partials
    k_mmx<<<256, 512, 0, stream>>>(Abf, zdT, parts);
    // out = d[i] * sum(parts) + b
    k_red<<<NN * FF / 2048, 256, 0, stream>>>(parts, d_, b, out);
}

// Round 9
// 68.731 us; speedup vs baseline: 1.1740x; 1.0020x over previous
//
#include <hip/hip_runtime.h>
#include <cstdint>

#define NN 4096
#define FF 512

typedef short bf16x8 __attribute__((ext_vector_type(8)));
typedef float f32x4 __attribute__((ext_vector_type(4)));
typedef float f32x16 __attribute__((ext_vector_type(16)));

__device__ __forceinline__ uint16_t f2bf(float f) {
    uint32_t u = __builtin_bit_cast(uint32_t, f);
    u += 0x7FFFu + ((u >> 16) & 1u);   // round-to-nearest-even
    return (uint16_t)(u >> 16);
}
__device__ __forceinline__ float bf2f(uint16_t h) {
    uint32_t u = (uint32_t)h << 16;
    return __builtin_bit_cast(float, u);
}

// ---------------------------------------------------------------------------
// k_prep: Abf[i][j] = bf16(adj[i][j] + (i==j)), d_i = rsqrt(1 + rowsum(adj))
// ---------------------------------------------------------------------------
__global__ __launch_bounds__(256) void k_prep(const float* __restrict__ adj,
                                              float* __restrict__ d,
                                              uint16_t* __restrict__ Abf) {
    const int row  = blockIdx.x * 4 + (threadIdx.x >> 6);
    const int lane = threadIdx.x & 63;
    const float4* p = (const float4*)(adj + (size_t)row * NN);
    float4 v[16];
    float s = 0.f;
#pragma unroll
    for (int i = 0; i < 16; ++i) {
        v[i] = p[lane + i * 64];
        s += (v[i].x + v[i].y) + (v[i].z + v[i].w);
    }
#pragma unroll
    for (int off = 1; off < 64; off <<= 1) s += __shfl_xor(s, off);
    const float di = rsqrtf(s + 1.0f);
    if (lane == 0) d[row] = di;
    uint16_t* outp = Abf + (size_t)row * NN;
#pragma unroll
    for (int i = 0; i < 16; ++i) {
        const int cb = (lane + i * 64) * 4;
        float a0 = v[i].x, a1 = v[i].y, a2 = v[i].z, a3 = v[i].w;
        if (cb + 0 == row) a0 += 1.0f;
        if (cb + 1 == row) a1 += 1.0f;
        if (cb + 2 == row) a2 += 1.0f;
        if (cb + 3 == row) a3 += 1.0f;
        ushort4 o;
        o.x = f2bf(a0); o.y = f2bf(a1); o.z = f2bf(a2); o.w = f2bf(a3);
        *(ushort4*)(outp + cb) = o;
    }
}

// ---------------------------------------------------------------------------
// k_xc / k_wc: f32 -> bf16 casts
// ---------------------------------------------------------------------------
__global__ __launch_bounds__(256) void k_xc(const float* __restrict__ x,
                                            uint16_t* __restrict__ xbf) {
    const size_t t4 = (size_t)blockIdx.x * 256 + threadIdx.x;
    float4 v = *(const float4*)(x + t4 * 4);
    ushort4 o;
    o.x = f2bf(v.x); o.y = f2bf(v.y); o.z = f2bf(v.z); o.w = f2bf(v.w);
    *(ushort4*)(xbf + t4 * 4) = o;
}

__global__ __launch_bounds__(256) void k_wc(const float* __restrict__ W,
                                            uint16_t* __restrict__ Wbf) {
    const size_t t4 = (size_t)blockIdx.x * 256 + threadIdx.x;
    float4 v = *(const float4*)(W + t4 * 4);
    ushort4 o;
    o.x = f2bf(v.x); o.y = f2bf(v.y); o.z = f2bf(v.z); o.w = f2bf(v.w);
    *(ushort4*)(Wbf + t4 * 4) = o;
}

// ---------------------------------------------------------------------------
// k_zt: zdT[n][k] = bf16(d[k] * z32[k][n])   (transpose+scale, via LDS)
// ---------------------------------------------------------------------------
__global__ __launch_bounds__(256) void k_zt(const float* __restrict__ z32,
                                            const float* __restrict__ d,
                                            uint16_t* __restrict__ zdT) {
    __shared__ uint16_t t[64][72];
    const int k0 = blockIdx.x * 64;
    const int n0 = blockIdx.y * 64;
    const int tid = threadIdx.x;
    const int r   = tid >> 4;
    const int c4  = tid & 15;
#pragma unroll
    for (int pass = 0; pass < 4; ++pass) {
        const int row = pass * 16 + r;
        float4 v = *(const float4*)(z32 + (size_t)(k0 + row) * FF + n0 + c4 * 4);
        const float dk = d[k0 + row];
        t[c4 * 4 + 0][row] = f2bf(v.x * dk);
        t[c4 * 4 + 1][row] = f2bf(v.y * dk);
        t[c4 * 4 + 2][row] = f2bf(v.z * dk);
        t[c4 * 4 + 3][row] = f2bf(v.w * dk);
    }
    __syncthreads();
#pragma unroll
    for (int pass = 0; pass < 2; ++pass) {
        const int cid = pass * 256 + tid;
        const int n  = cid >> 3;
        const int ch = cid & 7;
        *(uint4*)(zdT + (size_t)(n0 + n) * NN + k0 + ch * 8) = *(const uint4*)&t[n][ch * 8];
    }
}

// ---------------------------------------------------------------------------
// k_mm (small GEMM, R7/R8-verified): C = A[.][K] * Bt[.][K]^T, f32 out.
// ---------------------------------------------------------------------------
template <int BM, int BN, int K>
__global__ __launch_bounds__(256, 4) void k_mm(const uint16_t* __restrict__ A,
                                               const uint16_t* __restrict__ Bt,
                                               float* __restrict__ outp) {
    constexpr int NTC   = FF / BN;
    constexpr int NT    = K / 64;
    constexpr int MFR   = BM / 32;
    constexpr int NFR   = BN / 32;
    constexpr int LPT_A = BM / 32;
    constexpr int LPT_B = BN / 32;

    __shared__ uint16_t As[BM * 64];
    __shared__ uint16_t Bs[BN * 64];

    const int id   = blockIdx.x;
    const int mt   = id / NTC;
    const int nt   = id % NTC;
    const int m0 = mt * BM;
    const int n0 = nt * BN;

    const int tid  = threadIdx.x;
    const int w    = tid >> 6;
    const int lane = tid & 63;
    const int wm = w >> 1, wn = w & 1;

    f32x4 acc[MFR][NFR] = {};

    for (int t = 0; t < NT; ++t) {
        const int ktb = t * 64;
#pragma unroll
        for (int i = 0; i < LPT_A; ++i) {
            const int boff = i * 4096 + tid * 16;
            const int row  = boff >> 7;
            const int q    = (boff >> 4) & 7;
            const int c    = q ^ (row & 7);
            const uint16_t* src = A + (size_t)(m0 + row) * K + ktb + c * 8;
            __builtin_amdgcn_global_load_lds(
                (const __attribute__((address_space(1))) void*)src,
                (__attribute__((address_space(3))) void*)&As[boff >> 1],
                16, 0, 0);
        }
#pragma unroll
        for (int i = 0; i < LPT_B; ++i) {
            const int boff = i * 4096 + tid * 16;
            const int row  = boff >> 7;
            const int q    = (boff >> 4) & 7;
            const int c    = q ^ (row & 7);
            const uint16_t* src = Bt + (size_t)(n0 + row) * K + ktb + c * 8;
            __builtin_amdgcn_global_load_lds(
                (const __attribute__((address_space(1))) void*)src,
                (__attribute__((address_space(3))) void*)&Bs[boff >> 1],
                16, 0, 0);
        }
        __syncthreads();
#pragma unroll
        for (int kk = 0; kk < 2; ++kk) {
            const int cl = kk * 4 + (lane >> 4);
            bf16x8 af[MFR], bfr[NFR];
#pragma unroll
            for (int mf = 0; mf < MFR; ++mf) {
                const int r = wm * (MFR * 16) + mf * 16 + (lane & 15);
                af[mf] = *(const bf16x8*)&As[r * 64 + ((cl ^ (r & 7)) << 3)];
            }
#pragma unroll
            for (int nf = 0; nf < NFR; ++nf) {
                const int r = wn * (NFR * 16) + nf * 16 + (lane & 15);
                bfr[nf] = *(const bf16x8*)&Bs[r * 64 + ((cl ^ (r & 7)) << 3)];
            }
#pragma unroll
            for (int mf = 0; mf < MFR; ++mf)
#pragma unroll
                for (int nf = 0; nf < NFR; ++nf)
                    acc[mf][nf] = __builtin_amdgcn_mfma_f32_16x16x32_bf16(
                        af[mf], bfr[nf], acc[mf][nf], 0, 0, 0);
        }
        __syncthreads();
    }

    const int rbase = m0 + wm * (MFR * 16) + ((lane >> 4) << 2);
    const int cbase = n0 + wn * (NFR * 16) + (lane & 15);
#pragma unroll
    for (int mf = 0; mf < MFR; ++mf)
#pragma unroll
        for (int nf = 0; nf < NFR; ++nf) {
            const int col = cbase + nf * 16;
#pragma unroll
            for (int r = 0; r < 4; ++r) {
                const int row = rbase + mf * 16 + r;
                outp[(size_t)row * FF + col] = acc[mf][nf][r];
            }
        }
}

// ---------------------------------------------------------------------------
// k_mmx (big GEMM, LDS-read-halved): parts[ks] = A @ Bt^T k-slice, bf16 out.
// 32x32x16 MFMA: 1 ds_read_b128 feeds 32 FLOP/byte (vs 16 with 16x16 frags) —
// attacks the measured LDS-pipe ceiling (ds_read_b128 ~12cy, 58% busy in R1).
// BM=BN=128, 256 thr = 4 waves (2x2), wave tile 64x64 = 2x2 of 32x32 frags.
// BK=64, double-buffer, ring-2 counted vmcnt(8). 512 blocks = 2/CU (64KB LDS,
// launch_bounds(256,2)). 8-slot XOR chunk swizzle [R6-R8 verified].
// 32x32 C/D layout col=lane&31, row=(r&3)+8*(r>>2)+4*(lane>>5) [R3/R4 verified].
// ---------------------------------------------------------------------------
__global__ __launch_bounds__(256, 2) void k_mmx(const uint16_t* __restrict__ A,
                                                const uint16_t* __restrict__ Bt,
                                                uint16_t* __restrict__ parts) {
    constexpr int BM = 128, BN = 128, K = NN, SPLITK = 4;
    constexpr int NTC   = FF / BN;        // 4
    constexpr int KSLEN = K / SPLITK;     // 1024
    constexpr int NT    = KSLEN / 64;     // 16
    constexpr int MTX   = (NN / BM) / 8;  // 4

    __shared__ uint16_t As[2][BM * 64];   // 2 x 16 KB
    __shared__ uint16_t Bs[2][BN * 64];   // 2 x 16 KB

    // XCD-grouped: id&7 = XCD; one m-stripe's 16 (nt,ks) blocks co-run per XCD.
    const int id   = blockIdx.x;          // 0..511
    const int xcd  = id & 7;
    const int slot = id >> 3;             // 0..63
    const int mt   = xcd * MTX + slot / (NTC * SPLITK);
    const int rem  = slot % (NTC * SPLITK);
    const int nt   = rem % NTC;
    const int ks   = rem / NTC;
    const int m0 = mt * BM;
    const int n0 = nt * BN;
    const int k0 = ks * KSLEN;

    const int tid  = threadIdx.x;
    const int w    = tid >> 6;
    const int lane = tid & 63;
    const int wm = w >> 1, wn = w & 1;

    f32x16 acc[2][2] = {};

    auto STAGE = [&](int t, int buf) {
        const int ktb = k0 + t * 64;
#pragma unroll
        for (int i = 0; i < 4; ++i) {      // A: 16 KB
            const int boff = i * 4096 + tid * 16;
            const int row  = boff >> 7;    // 0..127 (128 B rows)
            const int q    = (boff >> 4) & 7;
            const int c    = q ^ (row & 7);
            const uint16_t* src = A + (size_t)(m0 + row) * K + ktb + c * 8;
            __builtin_amdgcn_global_load_lds(
                (const __attribute__((address_space(1))) void*)src,
                (__attribute__((address_space(3))) void*)&As[buf][boff >> 1],
                16, 0, 0);
        }
#pragma unroll
        for (int i = 0; i < 4; ++i) {      // B: 16 KB
            const int boff = i * 4096 + tid * 16;
            const int row  = boff >> 7;
            const int q    = (boff >> 4) & 7;
            const int c    = q ^ (row & 7);
            const uint16_t* src = Bt + (size_t)(n0 + row) * K + ktb + c * 8;
            __builtin_amdgcn_global_load_lds(
                (const __attribute__((address_space(1))) void*)src,
                (__attribute__((address_space(3))) void*)&Bs[buf][boff >> 1],
                16, 0, 0);
        }
    };

    auto COMPUTE = [&](int buf) {
#pragma unroll
        for (int kk = 0; kk < 4; ++kk) {             // 4 k-slices of 16
            const int cl = kk * 2 + (lane >> 5);     // k-chunk 0..7
            bf16x8 af[2], bfr[2];
#pragma unroll
            for (int mf = 0; mf < 2; ++mf) {
                const int r = wm * 64 + mf * 32 + (lane & 31);
                af[mf] = *(const bf16x8*)&As[buf][r * 64 + ((cl ^ (r & 7)) << 3)];
            }
#pragma unroll
            for (int nf = 0; nf < 2; ++nf) {
                const int r = wn * 64 + nf * 32 + (lane & 31);
                bfr[nf] = *(const bf16x8*)&Bs[buf][r * 64 + ((cl ^ (r & 7)) << 3)];
            }
#pragma unroll
            for (int mf = 0; mf < 2; ++mf)
#pragma unroll
                for (int nf = 0; nf < 2; ++nf)
                    acc[mf][nf] = __builtin_amdgcn_mfma_f32_32x32x16_bf16(
                        af[mf], bfr[nf], acc[mf][nf], 0, 0, 0);
        }
    };

    STAGE(0, 0);
    for (int t = 0; t < NT - 1; ++t) {
        STAGE(t + 1, (t + 1) & 1);
        asm volatile("s_waitcnt vmcnt(8)" ::: "memory");  // next tile's 8 stay in flight
        __builtin_amdgcn_s_barrier();
        COMPUTE(t & 1);
        __builtin_amdgcn_s_barrier();   // fence before buf t&1 overwrite next iter
    }
    asm volatile("s_waitcnt vmcnt(0)" ::: "memory");
    __builtin_amdgcn_s_barrier();
    COMPUTE((NT - 1) & 1);

    // epilogue: bf16 partials. 32x32 C/D: col=lane&31, row=(r&3)+8*(r>>2)+4*(lane>>5)
    uint16_t* dst = parts + (size_t)ks * NN * FF;
    const int rb = m0 + wm * 64 + ((lane >> 5) << 2);
    const int cb = n0 + wn * 64 + (lane & 31);
#pragma unroll
    for (int mf = 0; mf < 2; ++mf)
#pragma unroll
        for (int nf = 0; nf < 2; ++nf) {
            const int gcol = cb + nf * 32;
#pragma unroll
            for (int r = 0; r < 16; ++r) {
                const int grow = rb + mf * 32 + (r & 3) + ((r >> 2) << 3);
                dst[(size_t)grow * FF + gcol] = f2bf(acc[mf][nf][r]);
            }
        }
}

// ---------------------------------------------------------------------------
// k_red: out[i][j] = d[i] * sum_p bf2f(parts[p][i][j]) + b[j]
// ---------------------------------------------------------------------------
__global__ __launch_bounds__(256) void k_red(const uint16_t* __restrict__ parts,
                                             const float* __restrict__ d,
                                             const float* __restrict__ b,
                                             float* __restrict__ out) {
    constexpr size_t STRIDE = (size_t)NN * FF;
    const size_t g   = (size_t)blockIdx.x * 256 + threadIdx.x;   // ushort8 id
    const int    row = (int)((g * 8) >> 9);
    const int    col = (int)((g * 8) & 511);
    float s[8] = {};
#pragma unroll
    for (int p = 0; p < 4; ++p) {
        ushort4 v0 = *(const ushort4*)(parts + p * STRIDE + g * 8);
        ushort4 v1 = *(const ushort4*)(parts + p * STRIDE + g * 8 + 4);
        s[0] += bf2f(v0.x); s[1] += bf2f(v0.y); s[2] += bf2f(v0.z); s[3] += bf2f(v0.w);
        s[4] += bf2f(v1.x); s[5] += bf2f(v1.y); s[6] += bf2f(v1.z); s[7] += bf2f(v1.w);
    }
    const float di = d[row];
    float4 o0, o1;
    o0.x = s[0] * di + b[col + 0];
    o0.y = s[1] * di + b[col + 1];
    o0.z = s[2] * di + b[col + 2];
    o0.w = s[3] * di + b[col + 3];
    o1.x = s[4] * di + b[col + 4];
    o1.y = s[5] * di + b[col + 5];
    o1.z = s[6] * di + b[col + 6];
    o1.w = s[7] * di + b[col + 7];
    *(float4*)(out + g * 8)     = o0;
    *(float4*)(out + g * 8 + 4) = o1;
}

// ---------------------------------------------------------------------------
extern "C" void kernel_launch(void* const* d_in, const int* in_sizes, int n_in,
                              void* d_out, int out_size, void* d_ws, size_t ws_size,
                              hipStream_t stream) {
    const float* x   = (const float*)d_in[0];   // [4096][512]
    const float* adj = (const float*)d_in[1];   // [4096][4096]
    const float* W   = (const float*)d_in[2];   // [512][512]
    const float* b   = (const float*)d_in[3];   // [512]
    float* out = (float*)d_out;                 // [4096][512] f32

    char* ws = (char*)d_ws;
    float*    d_    = (float*)ws;                                 // 16 KB (pad 64K)
    uint16_t* Abf   = (uint16_t*)(ws + 65536);                    // 32 MB
    uint16_t* zdT   = Abf + (size_t)NN * NN;                      // 4 MB
    uint16_t* xbf   = zdT + (size_t)FF * NN;                      // 4 MB
    uint16_t* Wbf   = xbf + (size_t)NN * FF;                      // 0.5 MB
    float*    z32   = (float*)(Wbf + (size_t)FF * FF);            // 8 MB
    uint16_t* parts = (uint16_t*)(z32 + (size_t)NN * FF);         // 16 MB (4 x 4MB bf16)

    k_wc<<<FF * FF / 1024, 256, 0, stream>>>(W, Wbf);
    k_xc<<<NN * FF / 1024, 256, 0, stream>>>(x, xbf);
    k_prep<<<NN / 4, 256, 0, stream>>>(adj, d_, Abf);
    // z = x @ W^T  (BM=64, BN=64, 512 blocks = 2/CU)
    k_mm<64, 64, FF><<<512, 256, 0, stream>>>(xbf, Wbf, z32);
    // zdT[n][k] = d_k * z[k][n] in bf16
    k_zt<<<dim3(NN / 64, FF / 64), 256, 0, stream>>>(z32, d_, zdT);
    // parts[ks] = A @ zdT^T (k-slice ks): 32x32 frags, ring-2, bf16 partials
    k_mmx<<<512, 256, 0, stream>>>(Abf, zdT, parts);
    // out = d[i] * sum(parts) + b
    k_red<<<NN * FF / 2048, 256, 0, stream>>>(parts, d_, b, out);
}